// Round 5
// baseline (439.582 us; speedup 1.0000x reference)
//
#include <hip/hip_runtime.h>
#include <hip/hip_bf16.h>
#include <cstdint>

#define B_ 8
#define T_ 2048
#define E_ 256
#define K_ 512
#define KS_ 9
#define L_ 8192
#define PAD_ 4
#define TP_ (T_ + 2 * PAD_)   // 2056
#define KK_ (E_ * KS_)        // 2304

// fp8 scaling: feats stored as fp8*64, U/final stored as fp8*16.
// S and V accumulators are 1024x true value -> multiply by 2^-10 in epilogue.
#define FEAT_SCALE 64.0f
#define W_SCALE 16.0f
#define INV_SS 9.765625e-4f   // 2^-10

typedef __bf16 bf16x8 __attribute__((ext_vector_type(8)));
typedef float f32x4 __attribute__((ext_vector_type(4)));
typedef float f32x16 __attribute__((ext_vector_type(16)));

__device__ __forceinline__ unsigned short f2bf(float f) {
  union { float f; unsigned int u; } a; a.f = f;
  unsigned int r = (a.u + 0x7FFFu + ((a.u >> 16) & 1u)) >> 16;
  return (unsigned short)r;
}

__device__ __forceinline__ unsigned char f2fp8(float v) {
  return (unsigned char)(__builtin_amdgcn_cvt_pk_fp8_f32(v, v, 0, false) & 0xFF);
}

__device__ __forceinline__ unsigned int pk4_fp8(float a, float b, float c, float d) {
  int v = __builtin_amdgcn_cvt_pk_fp8_f32(a, b, 0, false);
  v = __builtin_amdgcn_cvt_pk_fp8_f32(c, d, v, true);
  return (unsigned int)v;
}

__device__ __forceinline__ void gld_lds16(const void* g, void* l) {
  __builtin_amdgcn_global_load_lds(
      (const __attribute__((address_space(1))) unsigned int*)g,
      (__attribute__((address_space(3))) unsigned int*)l, 16, 0, 0);
}

__device__ __forceinline__ f32x4 mfma_bf16(bf16x8 a, bf16x8 b, f32x4 c) {
  return __builtin_amdgcn_mfma_f32_16x16x32_bf16(a, b, c, 0, 0, 0);
}

__device__ __forceinline__ f32x16 mfma32_fp8(long long a, long long b, f32x16 c) {
  return __builtin_amdgcn_mfma_f32_32x32x16_fp8_fp8(a, b, c, 0, 0, 0);
}

// ---------------- prep: embed gather + zero halo, cast to bf16 ----------------
__global__ __launch_bounds__(256) void k_embed(const int* __restrict__ ids,
                                               const float* __restrict__ emb,
                                               unsigned short* __restrict__ xpad) {
  int gid = blockIdx.x * 256 + threadIdx.x;
  int row = gid >> 6;
  int e4 = (gid & 63) << 2;
  int b = row / TP_;
  int tp = row - b * TP_;
  float4 v = make_float4(0.f, 0.f, 0.f, 0.f);
  if (tp >= PAD_ && tp < T_ + PAD_) {
    int id = ids[b * T_ + tp - PAD_];
    v = *(const float4*)(emb + (size_t)id * E_ + e4);
  }
  ushort4 o;
  o.x = f2bf(v.x); o.y = f2bf(v.y); o.z = f2bf(v.z); o.w = f2bf(v.w);
  *(ushort4*)(xpad + (size_t)row * E_ + e4) = o;
}

// ---------------- prep: conv_w [K,E,KS] -> W_t [K][j*256+e] bf16 ----------------
__global__ __launch_bounds__(256) void k_wt(const float* __restrict__ conv_w,
                                            unsigned short* __restrict__ wt) {
  int kk = blockIdx.x * 256 + threadIdx.x;
  int k = blockIdx.y;
  int j = kk >> 8, e = kk & 255;
  wt[(size_t)k * KK_ + kk] = f2bf(conv_w[(k * E_ + e) * KS_ + j]);
}

// ---------------- prep: U_w / final_w fp32 -> fp8 (x16) ----------------
__global__ __launch_bounds__(256) void k_cast(const float* __restrict__ U_w,
                                              const float* __restrict__ F_w,
                                              unsigned char* __restrict__ u8,
                                              unsigned char* __restrict__ f8) {
  int gid = blockIdx.x * 256 + threadIdx.x;
  const float* src = blockIdx.y ? F_w : U_w;
  unsigned char* dst = blockIdx.y ? f8 : u8;
  size_t base = (size_t)gid * 8;
  float4 v0 = *(const float4*)(src + base);
  float4 v1 = *(const float4*)(src + base + 4);
  uint2 o;
  o.x = pk4_fp8(v0.x * W_SCALE, v0.y * W_SCALE, v0.z * W_SCALE, v0.w * W_SCALE);
  o.y = pk4_fp8(v1.x * W_SCALE, v1.y * W_SCALE, v1.z * W_SCALE, v1.w * W_SCALE);
  *(uint2*)(dst + base) = o;
}

// ---------------- conv1d as MFMA GEMM (bf16 in, fp8 out x64) ----------------
// 512 threads = 8 waves (4 t-quarters x 2 k-halves), wave tile 32t x 64k,
// BK=64, double-buffered LDS, XOR-16B swizzle. acc = 32 VGPR -> 4 waves/EU.
__global__ __launch_bounds__(512, 4) void k_conv(const unsigned short* __restrict__ xpad,
                                                 const unsigned short* __restrict__ wt,
                                                 const float* __restrict__ conv_b,
                                                 unsigned char* __restrict__ feats) {
  __shared__ char At[2][16384];
  __shared__ char Bt[2][16384];
  const int tid = threadIdx.x;
  const int lane = tid & 63;
  const int q = lane >> 4, c = lane & 15;
  const int w = tid >> 6;
  const int wi = w >> 1, wj = w & 1;
  const int b = blockIdx.z;
  const int t0 = blockIdx.y * 128;
  const int n0 = blockIdx.x * 128;

  const char* xb = (const char*)(xpad + (size_t)b * TP_ * E_);
  const char* wb = (const char*)wt;

  // staging geometry: 2 rounds per tensor, unit u = rnd*512+tid.
  // row r = u>>3, 16B piece j stored at slot j^(r&7).
  const char* asrc[2]; const char* bsrc[2]; int ldso[2];
#pragma unroll
  for (int rnd = 0; rnd < 2; ++rnd) {
    int u = rnd * 512 + tid;
    int r = u >> 3;
    int j = (u & 7) ^ (r & 7);
    asrc[rnd] = xb + (size_t)(t0 + r) * 512 + j * 16;
    bsrc[rnd] = wb + (size_t)(n0 + r) * (KK_ * 2) + j * 16;
    ldso[rnd] = u * 16;
  }

  // frag read offsets [idx][h]: row*128 + ((4h+q)^(row&7))*16
  int offA[2][2], offB[4][2];
#pragma unroll
  for (int li = 0; li < 2; ++li) {
    int r = wi * 32 + li * 16 + c;
#pragma unroll
    for (int h = 0; h < 2; ++h) offA[li][h] = r * 128 + (((4 * h + q) ^ (r & 7)) << 4);
  }
#pragma unroll
  for (int ti = 0; ti < 4; ++ti) {
    int r = wj * 64 + ti * 16 + c;
#pragma unroll
    for (int h = 0; h < 2; ++h) offB[ti][h] = r * 128 + (((4 * h + q) ^ (r & 7)) << 4);
  }

  f32x4 acc[2][4];
  f32x4 zero = {0.f, 0.f, 0.f, 0.f};
#pragma unroll
  for (int i = 0; i < 2; ++i)
#pragma unroll
    for (int j = 0; j < 4; ++j) acc[i][j] = zero;

  // stage it 0 into buffer 0
#pragma unroll
  for (int rnd = 0; rnd < 2; ++rnd) {
    gld_lds16(asrc[rnd], At[0] + ldso[rnd]);
    gld_lds16(bsrc[rnd], Bt[0] + ldso[rnd]);
  }

  for (int it = 0; it < 36; ++it) {
    const int bsel = it & 1;
    __syncthreads();
    if (it != 35) {
      const int kkc = (it + 1) * 64;
      const int aofs = (kkc >> 8) * 512 + (kkc & 255) * 2;
      const int bofs = kkc * 2;
#pragma unroll
      for (int rnd = 0; rnd < 2; ++rnd) {
        gld_lds16(asrc[rnd] + aofs, At[bsel ^ 1] + ldso[rnd]);
        gld_lds16(bsrc[rnd] + bofs, Bt[bsel ^ 1] + ldso[rnd]);
      }
    }
    const char* aB = At[bsel];
    const char* bB = Bt[bsel];
#pragma unroll
    for (int h = 0; h < 2; ++h) {
      bf16x8 afr[2], bfr[4];
#pragma unroll
      for (int li = 0; li < 2; ++li) afr[li] = *(const bf16x8*)(aB + offA[li][h]);
#pragma unroll
      for (int ti = 0; ti < 4; ++ti) bfr[ti] = *(const bf16x8*)(bB + offB[ti][h]);
#pragma unroll
      for (int ti = 0; ti < 4; ++ti)
#pragma unroll
        for (int li = 0; li < 2; ++li)
          acc[li][ti] = mfma_bf16(afr[li], bfr[ti], acc[li][ti]);
    }
  }

  // epilogue: +bias, relu, fp8 store. C/D: row(t)=q*4+rr, col(k)=c
#pragma unroll
  for (int ti = 0; ti < 4; ++ti) {
    int k = n0 + wj * 64 + ti * 16 + c;
    float bias = conv_b[k];
#pragma unroll
    for (int li = 0; li < 2; ++li) {
      int tb = t0 + wi * 32 + li * 16 + q * 4;
#pragma unroll
      for (int rr = 0; rr < 4; ++rr) {
        float v = fmaxf(acc[li][ti][rr] + bias, 0.f) * FEAT_SCALE;
        feats[((size_t)(b * T_ + tb + rr)) * K_ + k] = f2fp8(v);
      }
    }
  }
}

// ---------------- fused label-attention ----------------
// 512 threads = 8 waves (4 L-quarters x 2 T-halves), MFMA 32x32x16 fp8.
// U and W tiles (128 rows x 512 B each) resident in LDS for the whole block
// (deterministic -- R4's register plan was defeated by the compiler).
// F tile double-buffered in 8 KB chunks (64 t-cols x 128 K).
// All LDS frag reads b64 with 16B-unit XOR swizzle: exactly 2-way (free).
__global__ __launch_bounds__(512, 2) void k_attn(const unsigned char* __restrict__ feats,
                                                 const unsigned char* __restrict__ u8,
                                                 const unsigned char* __restrict__ f8,
                                                 const float* __restrict__ final_b,
                                                 float* __restrict__ out) {
  __shared__ char Usm[65536];     // 128 rows x 512 B, unit j at slot j^(r&31)
  __shared__ char Wsm[65536];
  __shared__ char Fsm[2][8192];   // 64 rows x 128 B, unit j at slot j^(r&7)
  __shared__ float red[512];
  const int tid = threadIdx.x;
  const int lane = tid & 63;
  const int q2 = lane >> 5, c32 = lane & 31;
  const int w = tid >> 6;
  const int wi = w >> 1;   // L quarter (32 rows)
  const int wj = w & 1;    // T half (32 cols of 64-col t-tile)
  const int b = blockIdx.y;
  const int l0 = blockIdx.x * 128;

  const unsigned char* fb = feats + (size_t)b * T_ * K_;

  // ---- stage U/W once: 8 rounds x 512 threads x 16 B per matrix ----
#pragma unroll
  for (int rnd = 0; rnd < 8; ++rnd) {
    int s = rnd * 512 + tid;
    int r = s >> 5;
    int j = (s & 31) ^ (r & 31);
    gld_lds16(u8 + (size_t)(l0 + r) * K_ + j * 16, Usm + s * 16);
    gld_lds16(f8 + (size_t)(l0 + r) * K_ + j * 16, Wsm + s * 16);
  }

  // ---- F staging: 1 unit/thread/chunk ----
  const int fr = tid >> 3;                  // chunk row 0..63
  const int fj = (tid & 7) ^ (fr & 7);      // global 16B piece
  const unsigned char* fsrc = fb + (size_t)fr * K_ + fj * 16;  // + tt*64*K + kq*128
  char* const fdst = (char*)Fsm + tid * 16;                    // + bsel*8192
  gld_lds16(fsrc, fdst);   // it=0 chunk (tt=0,kq=0) into buf 0

  // ---- frag read bases ----
  const char* uRow = Usm + (wi * 32 + c32) * 512 + q2 * 8;  // + ((ksg^c32)<<4)
  const char* wRow = Wsm + (wi * 32 + c32) * 512 + q2 * 8;
  const int brow = wj * 32 + c32;
  const int bbase = brow * 128 + q2 * 8;                    // + ((ks^(brow&7))<<4)
  const int b7 = brow & 7;

  f32x16 accS, accV;
  float num[16], den[16];
#pragma unroll
  for (int r = 0; r < 16; ++r) { accS[r] = 0.f; accV[r] = 0.f; num[r] = 0.f; den[r] = 0.f; }

  // it = tt*4 + kq: 32 t-tiles (64 cols) x 4 K-quarters (128 each)
  for (int it = 0; it < 128; ++it) {
    const int bsel = it & 1;
    __syncthreads();   // buf[bsel] staged (vmcnt drain); reads of buf[bsel^1] done
    if (it != 127) {
      const int nit = it + 1;
      const int ofs = (nit >> 2) * (64 * K_) + (nit & 3) * 128;
      gld_lds16(fsrc + ofs, fdst + (bsel ^ 1) * 8192);
    }
    const char* fB = Fsm[bsel];
    const int kq8 = (it & 3) * 8;
#pragma unroll
    for (int ks = 0; ks < 8; ++ks) {
      const int sa = ((kq8 + ks) ^ c32) << 4;
      const int sb = (ks ^ b7) << 4;
      long long ua = *(const long long*)(uRow + sa);
      long long wa = *(const long long*)(wRow + sa);
      long long fa = *(const long long*)(fB + bbase + sb);
      accS = mfma32_fp8(ua, fa, accS);
      accV = mfma32_fp8(wa, fa, accV);
    }
    if ((it & 3) == 3) {
      // end of K for this t-tile: softmax-weighted accumulate, reset accs.
      // scores are O(0.01): exp without max-shift is safe.
#pragma unroll
      for (int r = 0; r < 16; ++r) {
        float p = __expf(accS[r] * INV_SS);
        den[r] += p;
        num[r] += p * (accV[r] * INV_SS);
        accS[r] = 0.f;
        accV[r] = 0.f;
      }
    }
  }

  // reduce over 32 t-columns (c32 lanes; q2 halves hold different L-rows)
#pragma unroll
  for (int r = 0; r < 16; ++r) {
#pragma unroll
    for (int m = 1; m < 32; m <<= 1) {
      num[r] += __shfl_xor(num[r], m, 64);
      den[r] += __shfl_xor(den[r], m, 64);
    }
  }
  if (c32 == 0) {
#pragma unroll
    for (int r = 0; r < 16; ++r) {
      // C/D 32x32: row = (reg&3) + 8*(reg>>2) + 4*(lane>>5)
      int ll = wi * 32 + (r & 3) + 8 * (r >> 2) + 4 * q2;
      red[wj * 256 + ll] = num[r];
      red[wj * 256 + 128 + ll] = den[r];
    }
  }
  __syncthreads();
  if (tid < 128) {
    int l = l0 + tid;
    float n = red[tid] + red[256 + tid];
    float d = red[128 + tid] + red[384 + tid];
    out[(size_t)b * L_ + l] = n / d + final_b[l];
  }
}

// ---------------- BCE-with-logits mean ----------------
__global__ __launch_bounds__(256) void k_loss(const float* __restrict__ yhat,
                                              const float* __restrict__ target,
                                              float* __restrict__ loss) {
  int gid = blockIdx.x * 256 + threadIdx.x;
  float s = 0.f;
  for (int i = gid; i < B_ * L_; i += 64 * 256) {
    float y = yhat[i], t = target[i];
    s += fmaxf(y, 0.f) - y * t + log1pf(__expf(-fabsf(y)));
  }
#pragma unroll
  for (int m = 1; m < 64; m <<= 1) s += __shfl_xor(s, m, 64);
  if ((threadIdx.x & 63) == 0) atomicAdd(loss, s * (1.0f / (B_ * L_)));
}

extern "C" void kernel_launch(void* const* d_in, const int* in_sizes, int n_in,
                              void* d_out, int out_size, void* d_ws, size_t ws_size,
                              hipStream_t stream) {
  const int* ids = (const int*)d_in[0];
  const float* target = (const float*)d_in[3];
  const float* emb = (const float*)d_in[4];
  const float* conv_w = (const float*)d_in[5];
  const float* conv_b = (const float*)d_in[6];
  const float* U_w = (const float*)d_in[7];
  const float* F_w = (const float*)d_in[8];
  const float* final_b = (const float*)d_in[9];
  float* out = (float*)d_out;

  char* ws = (char*)d_ws;
  unsigned short* xpad = (unsigned short*)ws;                    // bf16 B*TP*E
  size_t off = (size_t)B_ * TP_ * E_ * 2;
  unsigned short* wt = (unsigned short*)(ws + off);              // bf16 K*KK
  off += (size_t)K_ * KK_ * 2;
  unsigned char* u8 = (unsigned char*)(ws + off);                // fp8 L*K
  off += (size_t)L_ * K_;
  unsigned char* f8 = (unsigned char*)(ws + off);                // fp8 L*K
  off += (size_t)L_ * K_;
  unsigned char* feats = (unsigned char*)(ws + off);             // fp8 B*T*K
  off += (size_t)B_ * T_ * K_;
  if (ws_size < off) return;

  k_embed<<<dim3((B_ * TP_ * 64) / 256), 256, 0, stream>>>(ids, emb, xpad);
  k_wt<<<dim3(KK_ / 256, K_), 256, 0, stream>>>(conv_w, wt);
  k_cast<<<dim3((L_ * K_ / 8) / 256, 2), 256, 0, stream>>>(U_w, F_w, u8, f8);
  k_conv<<<dim3(K_ / 128, T_ / 128, B_), 512, 0, stream>>>(xpad, wt, conv_b, feats);
  k_attn<<<dim3(L_ / 128, B_), 512, 0, stream>>>(feats, u8, f8, final_b, out);
  hipMemsetAsync(out + B_ * L_, 0, sizeof(float), stream);
  k_loss<<<dim3(64), 256, 0, stream>>>(out, target, out + B_ * L_);
}

// Round 6
// 346.832 us; speedup vs baseline: 1.2674x; 1.2674x over previous
//
#include <hip/hip_runtime.h>
#include <hip/hip_bf16.h>
#include <cstdint>

#define B_ 8
#define T_ 2048
#define E_ 256
#define K_ 512
#define KS_ 9
#define L_ 8192
#define PAD_ 4
#define TP_ (T_ + 2 * PAD_)   // 2056
#define KK_ (E_ * KS_)        // 2304

// fp8 scaling: feats stored as fp8*64, U/final stored as fp8*16.
// S and V accumulators are 1024x true value -> multiply by 2^-10 in epilogue.
#define FEAT_SCALE 64.0f
#define W_SCALE 16.0f
#define INV_SS 9.765625e-4f   // 2^-10

typedef __bf16 bf16x8 __attribute__((ext_vector_type(8)));
typedef float f32x4 __attribute__((ext_vector_type(4)));
typedef float f32x16 __attribute__((ext_vector_type(16)));

__device__ __forceinline__ unsigned short f2bf(float f) {
  union { float f; unsigned int u; } a; a.f = f;
  unsigned int r = (a.u + 0x7FFFu + ((a.u >> 16) & 1u)) >> 16;
  return (unsigned short)r;
}

__device__ __forceinline__ unsigned char f2fp8(float v) {
  return (unsigned char)(__builtin_amdgcn_cvt_pk_fp8_f32(v, v, 0, false) & 0xFF);
}

__device__ __forceinline__ unsigned int pk4_fp8(float a, float b, float c, float d) {
  int v = __builtin_amdgcn_cvt_pk_fp8_f32(a, b, 0, false);
  v = __builtin_amdgcn_cvt_pk_fp8_f32(c, d, v, true);
  return (unsigned int)v;
}

__device__ __forceinline__ void gld_lds16(const void* g, void* l) {
  __builtin_amdgcn_global_load_lds(
      (const __attribute__((address_space(1))) unsigned int*)g,
      (__attribute__((address_space(3))) unsigned int*)l, 16, 0, 0);
}

__device__ __forceinline__ f32x4 mfma_bf16(bf16x8 a, bf16x8 b, f32x4 c) {
  return __builtin_amdgcn_mfma_f32_16x16x32_bf16(a, b, c, 0, 0, 0);
}

__device__ __forceinline__ f32x16 mfma32_fp8(long long a, long long b, f32x16 c) {
  return __builtin_amdgcn_mfma_f32_32x32x16_fp8_fp8(a, b, c, 0, 0, 0);
}

// Pre-baked global swizzle for fp8 row-major [row][512] tensors (feats, u8, f8):
// 16B unit ku stored at slot (ku low3 ^ (row>>1)&7), 8B halves swapped by row parity.
// Bank audit for b64 frag reads (64 lanes, rows = c32): each 16B window serves
// 8 lanes x 8 B over 4 banks = exact data floor, no excess serialization.
__device__ __forceinline__ int swz_off(int k, int row) {
  int ku = k >> 4;
  int slot = (((ku & 7) ^ ((row >> 1) & 7)) | (ku & 24));
  return slot * 16 + ((((k >> 3) ^ row) & 1) << 3) + (k & 7);
}

// ---------------- prep: embed gather + zero halo, cast to bf16 ----------------
__global__ __launch_bounds__(256) void k_embed(const int* __restrict__ ids,
                                               const float* __restrict__ emb,
                                               unsigned short* __restrict__ xpad) {
  int gid = blockIdx.x * 256 + threadIdx.x;
  int row = gid >> 6;
  int e4 = (gid & 63) << 2;
  int b = row / TP_;
  int tp = row - b * TP_;
  float4 v = make_float4(0.f, 0.f, 0.f, 0.f);
  if (tp >= PAD_ && tp < T_ + PAD_) {
    int id = ids[b * T_ + tp - PAD_];
    v = *(const float4*)(emb + (size_t)id * E_ + e4);
  }
  ushort4 o;
  o.x = f2bf(v.x); o.y = f2bf(v.y); o.z = f2bf(v.z); o.w = f2bf(v.w);
  *(ushort4*)(xpad + (size_t)row * E_ + e4) = o;
}

// ---------------- prep: conv_w [K,E,KS] -> W_t [K][j*256+e] bf16 ----------------
__global__ __launch_bounds__(256) void k_wt(const float* __restrict__ conv_w,
                                            unsigned short* __restrict__ wt) {
  int kk = blockIdx.x * 256 + threadIdx.x;
  int k = blockIdx.y;
  int j = kk >> 8, e = kk & 255;
  wt[(size_t)k * KK_ + kk] = f2bf(conv_w[(k * E_ + e) * KS_ + j]);
}

// ---------------- prep: U_w / final_w fp32 -> fp8 (x16), pre-swizzled rows ----------------
__global__ __launch_bounds__(256) void k_cast(const float* __restrict__ U_w,
                                              const float* __restrict__ F_w,
                                              unsigned char* __restrict__ u8,
                                              unsigned char* __restrict__ f8) {
  int gid = blockIdx.x * 256 + threadIdx.x;
  const float* src = blockIdx.y ? F_w : U_w;
  unsigned char* dst = blockIdx.y ? f8 : u8;
  int l = gid >> 6;
  int k0 = (gid & 63) << 3;
  const float* s = src + (size_t)l * K_ + k0;
  float4 v0 = *(const float4*)(s);
  float4 v1 = *(const float4*)(s + 4);
  uint2 o;
  o.x = pk4_fp8(v0.x * W_SCALE, v0.y * W_SCALE, v0.z * W_SCALE, v0.w * W_SCALE);
  o.y = pk4_fp8(v1.x * W_SCALE, v1.y * W_SCALE, v1.z * W_SCALE, v1.w * W_SCALE);
  *(uint2*)(dst + (size_t)l * K_ + swz_off(k0, l)) = o;
}

// ---------------- conv1d as MFMA GEMM (bf16 in, fp8 out x64, swizzled rows) ----------------
__global__ __launch_bounds__(512, 4) void k_conv(const unsigned short* __restrict__ xpad,
                                                 const unsigned short* __restrict__ wt,
                                                 const float* __restrict__ conv_b,
                                                 unsigned char* __restrict__ feats) {
  __shared__ char At[2][16384];
  __shared__ char Bt[2][16384];
  const int tid = threadIdx.x;
  const int lane = tid & 63;
  const int q = lane >> 4, c = lane & 15;
  const int w = tid >> 6;
  const int wi = w >> 1, wj = w & 1;
  const int b = blockIdx.z;
  const int t0 = blockIdx.y * 128;
  const int n0 = blockIdx.x * 128;

  const char* xb = (const char*)(xpad + (size_t)b * TP_ * E_);
  const char* wb = (const char*)wt;

  const char* asrc[2]; const char* bsrc[2]; int ldso[2];
#pragma unroll
  for (int rnd = 0; rnd < 2; ++rnd) {
    int u = rnd * 512 + tid;
    int r = u >> 3;
    int j = (u & 7) ^ (r & 7);
    asrc[rnd] = xb + (size_t)(t0 + r) * 512 + j * 16;
    bsrc[rnd] = wb + (size_t)(n0 + r) * (KK_ * 2) + j * 16;
    ldso[rnd] = u * 16;
  }

  int offA[2][2], offB[4][2];
#pragma unroll
  for (int li = 0; li < 2; ++li) {
    int r = wi * 32 + li * 16 + c;
#pragma unroll
    for (int h = 0; h < 2; ++h) offA[li][h] = r * 128 + (((4 * h + q) ^ (r & 7)) << 4);
  }
#pragma unroll
  for (int ti = 0; ti < 4; ++ti) {
    int r = wj * 64 + ti * 16 + c;
#pragma unroll
    for (int h = 0; h < 2; ++h) offB[ti][h] = r * 128 + (((4 * h + q) ^ (r & 7)) << 4);
  }

  f32x4 acc[2][4];
  f32x4 zero = {0.f, 0.f, 0.f, 0.f};
#pragma unroll
  for (int i = 0; i < 2; ++i)
#pragma unroll
    for (int j = 0; j < 4; ++j) acc[i][j] = zero;

#pragma unroll
  for (int rnd = 0; rnd < 2; ++rnd) {
    gld_lds16(asrc[rnd], At[0] + ldso[rnd]);
    gld_lds16(bsrc[rnd], Bt[0] + ldso[rnd]);
  }

  for (int it = 0; it < 36; ++it) {
    const int bsel = it & 1;
    __syncthreads();
    if (it != 35) {
      const int kkc = (it + 1) * 64;
      const int aofs = (kkc >> 8) * 512 + (kkc & 255) * 2;
      const int bofs = kkc * 2;
#pragma unroll
      for (int rnd = 0; rnd < 2; ++rnd) {
        gld_lds16(asrc[rnd] + aofs, At[bsel ^ 1] + ldso[rnd]);
        gld_lds16(bsrc[rnd] + bofs, Bt[bsel ^ 1] + ldso[rnd]);
      }
    }
    const char* aB = At[bsel];
    const char* bB = Bt[bsel];
#pragma unroll
    for (int h = 0; h < 2; ++h) {
      bf16x8 afr[2], bfr[4];
#pragma unroll
      for (int li = 0; li < 2; ++li) afr[li] = *(const bf16x8*)(aB + offA[li][h]);
#pragma unroll
      for (int ti = 0; ti < 4; ++ti) bfr[ti] = *(const bf16x8*)(bB + offB[ti][h]);
#pragma unroll
      for (int ti = 0; ti < 4; ++ti)
#pragma unroll
        for (int li = 0; li < 2; ++li)
          acc[li][ti] = mfma_bf16(afr[li], bfr[ti], acc[li][ti]);
    }
  }

  // epilogue: +bias, relu, fp8 store into the swizzled feats layout.
#pragma unroll
  for (int ti = 0; ti < 4; ++ti) {
    int k = n0 + wj * 64 + ti * 16 + c;
    float bias = conv_b[k];
#pragma unroll
    for (int li = 0; li < 2; ++li) {
      int tb = t0 + wi * 32 + li * 16 + q * 4;
#pragma unroll
      for (int rr = 0; rr < 4; ++rr) {
        float v = fmaxf(acc[li][ti][rr] + bias, 0.f) * FEAT_SCALE;
        int t = tb + rr;
        feats[(size_t)(b * T_ + t) * K_ + swz_off(k, t)] = f2fp8(v);
      }
    }
  }
}

// ---------------- fused label-attention ----------------
// 512 threads = 8 waves (4 L-quarters x 2 T-halves), MFMA 32x32x16 fp8.
// U/W frags loaded once (LDS -> 128 VGPRs); the same LDS region is then
// overwritten by the F double-buffer, so the compiler CANNOT re-read or
// rematerialize them (R4 failure mode). Steady state: 8 F b64-reads +
// 64 MFMAs per wave per 64-t-col chunk slice; one barrier per chunk.
__global__ __launch_bounds__(512, 2) void k_attn(const unsigned char* __restrict__ feats,
                                                 const unsigned char* __restrict__ u8,
                                                 const unsigned char* __restrict__ f8,
                                                 const float* __restrict__ final_b,
                                                 float* __restrict__ out) {
  __shared__ char smem[131072];
  __shared__ float red[512];
  const int tid = threadIdx.x;
  const int lane = tid & 63;
  const int q2 = lane >> 5, c32 = lane & 31;
  const int w = tid >> 6;
  const int wi = w >> 1;   // L quarter (32 rows)
  const int wj = w & 1;    // T half (32 cols of the 64-col chunk)
  const int b = blockIdx.y;
  const int l0 = blockIdx.x * 128;

  const unsigned char* fb = feats + (size_t)b * T_ * K_;

  // ---- stage U/W (pre-swizzled) identity into LDS: 64 KB each ----
  char* Us = smem;
  char* Ws = smem + 65536;
#pragma unroll
  for (int rr = 0; rr < 8; ++rr) {
    gld_lds16(u8 + (size_t)l0 * K_ + rr * 8192 + tid * 16, Us + rr * 8192 + tid * 16);
    gld_lds16(f8 + (size_t)l0 * K_ + rr * 8192 + tid * 16, Ws + rr * 8192 + tid * 16);
  }
  __syncthreads();

  // ---- pull the full-K A-fragments into registers (32 b64 each) ----
  const int arow = wi * 32 + c32;
  const int ab = arow * 512 + (((q2 ^ arow) & 1) << 3);
  const int a3 = (arow >> 1) & 7;
  long long uf[32], wf[32];
#pragma unroll
  for (int s = 0; s < 32; ++s) {
    int off = ab + ((((s & 7) ^ a3) | (s & 24)) << 4);
    uf[s] = *(const long long*)(Us + off);
    wf[s] = *(const long long*)(Ws + off);
  }
  __syncthreads();   // all waves done reading before F overwrites this region

  // ---- F double-buffer in the same LDS: 2 x 32 KB (64 t-cols x 512 B) ----
  char* const Fs0 = smem;
  char* const Fs1 = smem + 32768;
  const unsigned char* fsrc = fb + tid * 16;   // + tc*32768 + rr*8192
#pragma unroll
  for (int rr = 0; rr < 4; ++rr)
    gld_lds16(fsrc + rr * 8192, Fs0 + tid * 16 + rr * 8192);

  const int brow = wj * 32 + c32;
  const int bb = brow * 512 + (((q2 ^ brow) & 1) << 3);
  const int b3 = (brow >> 1) & 7;

  f32x16 accS, accV;
  float num[16], den[16];
#pragma unroll
  for (int r = 0; r < 16; ++r) { accS[r] = 0.f; accV[r] = 0.f; num[r] = 0.f; den[r] = 0.f; }

  for (int tc = 0; tc < 32; ++tc) {
    const int bsel = tc & 1;
    char* const cur = bsel ? Fs1 : Fs0;
    char* const nxt = bsel ? Fs0 : Fs1;
    __syncthreads();   // chunk tc staged; prior reads of the other buffer done
    if (tc != 31) {
      const unsigned char* nsrc = fsrc + (tc + 1) * 32768;
#pragma unroll
      for (int rr = 0; rr < 4; ++rr)
        gld_lds16(nsrc + rr * 8192, nxt + tid * 16 + rr * 8192);
    }
#pragma unroll
    for (int s = 0; s < 32; ++s) {
      long long fa = *(const long long*)(cur + bb + ((((s & 7) ^ b3) | (s & 24)) << 4));
      accS = mfma32_fp8(uf[s], fa, accS);
      accV = mfma32_fp8(wf[s], fa, accV);
    }
    // end of K for this chunk slice: softmax-weighted accumulate, reset.
    // scores are O(0.01): exp without max-shift is safe.
#pragma unroll
    for (int r = 0; r < 16; ++r) {
      float p = __expf(accS[r] * INV_SS);
      den[r] += p;
      num[r] += p * (accV[r] * INV_SS);
      accS[r] = 0.f;
      accV[r] = 0.f;
    }
  }

  // reduce over 32 t-columns (c32 lanes; q2 halves hold different L-rows)
#pragma unroll
  for (int r = 0; r < 16; ++r) {
#pragma unroll
    for (int m = 1; m < 32; m <<= 1) {
      num[r] += __shfl_xor(num[r], m, 64);
      den[r] += __shfl_xor(den[r], m, 64);
    }
  }
  if (c32 == 0) {
#pragma unroll
    for (int r = 0; r < 16; ++r) {
      // C/D 32x32: row = (reg&3) + 8*(reg>>2) + 4*(lane>>5)
      int ll = wi * 32 + (r & 3) + 8 * (r >> 2) + 4 * q2;
      red[wj * 256 + ll] = num[r];
      red[wj * 256 + 128 + ll] = den[r];
    }
  }
  __syncthreads();
  if (tid < 128) {
    int l = l0 + tid;
    float n = red[tid] + red[256 + tid];
    float d = red[128 + tid] + red[384 + tid];
    out[(size_t)b * L_ + l] = n / d + final_b[l];
  }
}

// ---------------- BCE-with-logits mean ----------------
__global__ __launch_bounds__(256) void k_loss(const float* __restrict__ yhat,
                                              const float* __restrict__ target,
                                              float* __restrict__ loss) {
  int gid = blockIdx.x * 256 + threadIdx.x;
  float s = 0.f;
  for (int i = gid; i < B_ * L_; i += 64 * 256) {
    float y = yhat[i], t = target[i];
    s += fmaxf(y, 0.f) - y * t + log1pf(__expf(-fabsf(y)));
  }
#pragma unroll
  for (int m = 1; m < 64; m <<= 1) s += __shfl_xor(s, m, 64);
  if ((threadIdx.x & 63) == 0) atomicAdd(loss, s * (1.0f / (B_ * L_)));
}

extern "C" void kernel_launch(void* const* d_in, const int* in_sizes, int n_in,
                              void* d_out, int out_size, void* d_ws, size_t ws_size,
                              hipStream_t stream) {
  const int* ids = (const int*)d_in[0];
  const float* target = (const float*)d_in[3];
  const float* emb = (const float*)d_in[4];
  const float* conv_w = (const float*)d_in[5];
  const float* conv_b = (const float*)d_in[6];
  const float* U_w = (const float*)d_in[7];
  const float* F_w = (const float*)d_in[8];
  const float* final_b = (const float*)d_in[9];
  float* out = (float*)d_out;

  char* ws = (char*)d_ws;
  unsigned short* xpad = (unsigned short*)ws;                    // bf16 B*TP*E
  size_t off = (size_t)B_ * TP_ * E_ * 2;
  unsigned short* wt = (unsigned short*)(ws + off);              // bf16 K*KK
  off += (size_t)K_ * KK_ * 2;
  unsigned char* u8 = (unsigned char*)(ws + off);                // fp8 L*K (swizzled)
  off += (size_t)L_ * K_;
  unsigned char* f8 = (unsigned char*)(ws + off);                // fp8 L*K (swizzled)
  off += (size_t)L_ * K_;
  unsigned char* feats = (unsigned char*)(ws + off);             // fp8 B*T*K (swizzled)
  off += (size_t)B_ * T_ * K_;
  if (ws_size < off) return;

  k_embed<<<dim3((B_ * TP_ * 64) / 256), 256, 0, stream>>>(ids, emb, xpad);
  k_wt<<<dim3(KK_ / 256, K_), 256, 0, stream>>>(conv_w, wt);
  k_cast<<<dim3((L_ * K_ / 8) / 256, 2), 256, 0, stream>>>(U_w, F_w, u8, f8);
  k_conv<<<dim3(K_ / 128, T_ / 128, B_), 512, 0, stream>>>(xpad, wt, conv_b, feats);
  k_attn<<<dim3(L_ / 128, B_), 512, 0, stream>>>(feats, u8, f8, final_b, out);
  hipMemsetAsync(out + B_ * L_, 0, sizeof(float), stream);
  k_loss<<<dim3(64), 256, 0, stream>>>(out, target, out + B_ * L_);
}